// Round 15
// baseline (44.243 us; speedup 1.0000x reference)
//
#include <hip/hip_runtime.h>
#include <math.h>

#define BD 8
#define SD 1024
#define ID 64
#define OD 128
#define NBD 6
#define TI 4            // i-tile per nk block
#define SCH 32          // s-chunk per block (Chebyshev re-init interval)
#define SS 8            // s per super-step (one MFMA wave each)
#define WPAD 136        // padded LDS row (bf16 elems): 272B stride, 4-bank skew
#define MPAD 130        // padded LDS row for weight transpose (floats)

typedef short bf16x8 __attribute__((ext_vector_type(8)));
typedef float f32x4 __attribute__((ext_vector_type(4)));

__device__ __forceinline__ ushort rne_bf16(float f) {
    union { float f; unsigned u; } cv; cv.f = f;
    return (ushort)((cv.u + 0x7FFFu + ((cv.u >> 16) & 1u)) >> 16);
}

// ---- Kernel A: proj + LN for 2 s; in-LDS weight transpose (no prep kernel) --
// 512 threads: i = t&127, mat = (t>>7)&1, sh = t>>8 (s-sub).
__global__ __launch_bounds__(512) void ln_kernel(
    const float* __restrict__ seq,    // (8,1024,64)
    const float* __restrict__ M,      // (128,64)  [i][j]
    const float* __restrict__ resW,   // (128,64)  [i][j]
    const float* __restrict__ gamma,
    const float* __restrict__ beta,
    ushort* __restrict__ xnT,         // (1024,8,128) bf16 [s][b][j]
    float* __restrict__ out)          // (8,1024,128) gets residual
{
    const int t   = threadIdx.x;
    const int i   = t & 127;
    const int mat = (t >> 7) & 1;     // wave-uniform
    const int sh  = t >> 8;           // wave-uniform
    const int s   = blockIdx.x * 2 + sh;

    __shared__ float Wt[2][ID][MPAD]; // 65 KB: [mat][j][i] transposed weights
    __shared__ float red[2][2][16];

    // ---- stage raw weights -> transposed LDS (coalesced global reads) ----
    {
        // 512 threads x 16 elems cover M (8192) ; same for resW
        #pragma unroll
        for (int k = 0; k < 16; ++k) {
            const int idx = t + k * 512;
            const int ii = idx >> 6, jj = idx & 63;
            Wt[0][jj][ii] = M[idx];
            Wt[1][jj][ii] = resW[idx];
        }
    }
    __syncthreads();

    // ---- per-thread weight column into VGPRs (conflict-free ds_read) ----
    float w[ID];
    #pragma unroll
    for (int j = 0; j < ID; ++j) w[j] = Wt[mat][j][i];
    const float gm = gamma[i];
    const float bt = beta[i];

    float acc[BD];
    #pragma unroll
    for (int b = 0; b < BD; ++b) {
        const float* __restrict__ xp = &seq[(b * SD + s) * ID];  // uniform -> s_load
        float a0 = 0.f, a1 = 0.f;
        #pragma unroll
        for (int j = 0; j < ID; j += 2) {
            a0 = fmaf(xp[j],     w[j],     a0);
            a1 = fmaf(xp[j + 1], w[j + 1], a1);
        }
        acc[b] = a0 + a1;
    }

    if (mat == 0) {
        float sum[BD], ssq[BD];
        #pragma unroll
        for (int b = 0; b < BD; ++b) { sum[b] = acc[b]; ssq[b] = acc[b] * acc[b]; }
        #pragma unroll
        for (int m = 1; m < 64; m <<= 1) {
            #pragma unroll
            for (int b = 0; b < BD; ++b) {
                sum[b] += __shfl_xor(sum[b], m, 64);
                ssq[b] += __shfl_xor(ssq[b], m, 64);
            }
        }
        if ((t & 63) == 0) {
            const int wv = (t >> 6) & 1;
            #pragma unroll
            for (int b = 0; b < BD; ++b) {
                red[sh][wv][b]     = sum[b];
                red[sh][wv][8 + b] = ssq[b];
            }
        }
    }
    __syncthreads();

    if (mat == 0) {
        #pragma unroll
        for (int b = 0; b < BD; ++b) {
            const float sm = red[sh][0][b] + red[sh][1][b];
            const float sq = red[sh][0][8 + b] + red[sh][1][8 + b];
            const float mu = sm * (1.0f / OD);
            const float vr = sq * (1.0f / OD) - mu * mu;
            const float rstd = rsqrtf(vr + 1e-5f);
            const float xv = (acc[b] - mu) * rstd * gm + bt;
            xnT[(s * BD + b) * OD + i] = rne_bf16(xv);   // coalesced b16 stores
        }
    } else {
        #pragma unroll
        for (int b = 0; b < BD; ++b)
            out[(b * SD + s) * OD + i] = acc[b];
    }
}

// ---- Kernel B: fused Chebyshev W-gen + MFMA, out += Nk (R14, validated) ----
__global__ __launch_bounds__(512, 6) void nk_kernel(
    const float* __restrict__ P,      // (128,128,6) raw [i][j][g]
    const ushort* __restrict__ xnT,   // [s][b][j] bf16
    float* __restrict__ out)          // (8,1024,128)
{
    const int sc = blockIdx.x;        // s in [sc*SCH, (sc+1)*SCH)
    const int i0 = blockIdx.y * TI;
    const int t  = threadIdx.x;
    const int iw = t >> 7;            // 0..3 local i (W-gen role)
    const int jb = t & 127;
    const int wv = t >> 6;            // 0..7 wave id (MFMA role)
    const int l  = t & 63;

    __shared__ ushort Wl[SS][TI][WPAD];    // 8.7 KB
    __shared__ ushort Xl[SS][BD][WPAD];    // 17.4 KB
    __shared__ float  Cst[SS][BD][TI];     // 1 KB epilogue stage

    // ---- init 6 Chebyshev states for (i0+iw, jb) ----
    float Pv[NBD], kk[NBD], c0[NBD], c1[NBD];
    const int ig = i0 + iw;
    const float s0f = (float)(sc * SCH);
    #pragma unroll
    for (int g = 0; g < NBD; ++g) {
        Pv[g] = P[(ig * OD + jb) * NBD + g];               // L2-hot, once/block
        const float per = (float)(ig * (OD * NBD) + jb * NBD + g + 2); // exact int
        const float rp  = __builtin_amdgcn_rcpf(per);      // revolutions per step
        kk[g] = 2.0f * __builtin_amdgcn_cosf(rp);
        c1[g] = __builtin_amdgcn_cosf(__builtin_amdgcn_fractf(s0f * rp));
        c0[g] = __builtin_amdgcn_cosf(__builtin_amdgcn_fractf((s0f - 1.0f) * rp));
    }

    for (int u = 0; u < SCH / SS; ++u) {
        const int sb = sc * SCH + u * SS;
        // ---- stage xn tile: 8s x 8b x 128j bf16 = 16 KB (coalesced uint4) ----
        {
            const uint4* __restrict__ src = (const uint4*)(xnT + sb * (BD * OD));
            #pragma unroll
            for (int r = 0; r < 2; ++r) {
                const int e  = t + 512 * r;       // uint4 index (1024 total)
                const uint4 v = src[e];
                const int eo = e << 3;            // bf16 elem offset
                const int si = eo >> 10;
                const int b  = (eo >> 7) & 7;
                const int j0 = eo & 127;
                *(uint4*)&Xl[si][b][j0] = v;
            }
        }
        // ---- W-gen: 8 s x (i0+iw, jb), 12 FMA/element ----
        #pragma unroll
        for (int ssi = 0; ssi < SS; ++ssi) {
            float wvv = 0.f;
            #pragma unroll
            for (int g = 0; g < NBD; ++g) wvv = fmaf(Pv[g], c1[g], wvv);
            #pragma unroll
            for (int g = 0; g < NBD; ++g) {
                const float cn = fmaf(kk[g], c1[g], -c0[g]);   // Chebyshev step
                c0[g] = c1[g]; c1[g] = cn;
            }
            Wl[ssi][iw][jb] = rne_bf16(wvv);
        }
        __syncthreads();
        // ---- MFMA: wave wv handles s = sb + wv ----
        {
            f32x4 acc4 = {0.f, 0.f, 0.f, 0.f};
            #pragma unroll
            for (int m = 0; m < 4; ++m) {
                const bf16x8 a = *(const bf16x8*)&Xl[wv][l & 7][m * 32 + (l >> 4) * 8];
                const bf16x8 b = *(const bf16x8*)&Wl[wv][l & 3][m * 32 + (l >> 4) * 8];
                acc4 = __builtin_amdgcn_mfma_f32_16x16x32_bf16(a, b, acc4, 0, 0, 0);
            }
            const int col  = l & 15;
            const int rowg = l >> 4;
            if (col < TI && rowg < 2) {
                #pragma unroll
                for (int q = 0; q < 4; ++q)
                    Cst[wv][rowg * 4 + q][col] = acc4[q];
            }
        }
        __syncthreads();
        // ---- coalesced RMW: 256 threads, t -> (s=t>>5, b=(t>>2)&7, i=t&3) ----
        if (t < SS * BD * TI) {
            const int ii  = t & 3;
            const int b   = (t >> 2) & 7;
            const int sl2 = t >> 5;
            out[(b * SD + sb + sl2) * OD + i0 + ii] += Cst[sl2][b][ii];
        }
        __syncthreads();   // protect Wl/Xl/Cst before next super-step
    }
}

extern "C" void kernel_launch(void* const* d_in, const int* in_sizes, int n_in,
                              void* d_out, int out_size, void* d_ws, size_t ws_size,
                              hipStream_t stream) {
    const float* seq   = (const float*)d_in[0];
    const float* M     = (const float*)d_in[1];
    const float* P     = (const float*)d_in[2];
    const float* resW  = (const float*)d_in[3];
    const float* gamma = (const float*)d_in[4];
    const float* beta  = (const float*)d_in[5];
    float* out = (float*)d_out;

    ushort* xnT = (ushort*)d_ws;                        // 2 MB bf16 [s][b][j]

    ln_kernel<<<dim3(SD / 2), dim3(512), 0, stream>>>(seq, M, resW, gamma, beta,
                                                      xnT, out);
    nk_kernel<<<dim3(SD / SCH, OD / TI), dim3(512), 0, stream>>>(P, xnT, out);
}

// Round 17
// 26.361 us; speedup vs baseline: 1.6783x; 1.6783x over previous
//
#include <hip/hip_runtime.h>
#include <math.h>

#define BD 8
#define SD 1024
#define ID 64
#define OD 128
#define NBD 6
#define TI 4            // i-tile per nk block
#define SCH 32          // s-chunk per block (Chebyshev re-init interval)
#define SS 8            // s per super-step (one MFMA wave each)
#define WPAD 136        // padded LDS row (bf16 elems)

typedef short bf16x8 __attribute__((ext_vector_type(8)));
typedef float f32x4 __attribute__((ext_vector_type(4)));
typedef ushort ushortx8 __attribute__((ext_vector_type(8)));

__device__ __forceinline__ ushort rne_bf16(float f) {
    union { float f; unsigned u; } cv; cv.f = f;
    return (ushort)((cv.u + 0x7FFFu + ((cv.u >> 16) & 1u)) >> 16);
}
__device__ __forceinline__ float bf16_to_f(ushort u) {
    union { unsigned u; float f; } cv; cv.u = ((unsigned)u) << 16;
    return cv.f;
}

__device__ __forceinline__ bf16x8 pack8(float4 a, float4 b) {
    union { ushort u[8]; bf16x8 v; } p;
    p.u[0] = rne_bf16(a.x); p.u[1] = rne_bf16(a.y);
    p.u[2] = rne_bf16(a.z); p.u[3] = rne_bf16(a.w);
    p.u[4] = rne_bf16(b.x); p.u[5] = rne_bf16(b.y);
    p.u[6] = rne_bf16(b.z); p.u[7] = rne_bf16(b.w);
    return p.v;
}

// split x into hi (bf16) + lo (bf16 of remainder): hi+lo ~ fp24 accuracy
__device__ __forceinline__ void pack8_split(float4 a, float4 b,
                                            bf16x8* hi, bf16x8* lo) {
    union { ushort u[8]; bf16x8 v; } ph, pl;
    const float e[8] = {a.x, a.y, a.z, a.w, b.x, b.y, b.z, b.w};
    #pragma unroll
    for (int k = 0; k < 8; ++k) {
        const ushort h = rne_bf16(e[k]);
        ph.u[k] = h;
        pl.u[k] = rne_bf16(e[k] - bf16_to_f(h));
    }
    *hi = ph.v; *lo = pl.v;
}

// ---- Kernel A: MFMA projections + LN. Block = 2 s x 8 b = 16 rows x 128 i --
// 256 threads / 4 waves; wave w owns cols [w*32, w*32+32).
// x_t uses split-precision A (hi+lo) -> near-f32; residual uses hi only.
__global__ __launch_bounds__(256) void ln_mfma(
    const float* __restrict__ seq,    // (8,1024,64)
    const float* __restrict__ M,      // (128,64) [i][j]
    const float* __restrict__ resW,   // (128,64) [i][j]
    const float* __restrict__ gamma,
    const float* __restrict__ beta,
    ushort* __restrict__ xnT,         // (1024,8,128) bf16 [s][b][j]
    float* __restrict__ out)          // (8,1024,128) gets residual
{
    const int t  = threadIdx.x;
    const int s0 = blockIdx.x * 2;
    const int w  = t >> 6;            // wave id -> col strip
    const int l  = t & 63;
    const int lr = l & 15;            // A-row / B-col selector
    const int lk = l >> 4;            // k-chunk selector

    __shared__ float Ct[16][132];     // x_t staging

    // ---- A fragments (split): row r=lr -> (b=r&7, sl=r>>3); k=j ----
    bf16x8 ahi[2], alo[2];
    {
        const int ba = lr & 7, sa = lr >> 3;
        const float* __restrict__ arow = &seq[(ba * SD + s0 + sa) * ID];
        #pragma unroll
        for (int ka = 0; ka < 2; ++ka) {
            const float4 v0 = *(const float4*)&arow[ka * 32 + lk * 8];
            const float4 v1 = *(const float4*)&arow[ka * 32 + lk * 8 + 4];
            pack8_split(v0, v1, &ahi[ka], &alo[ka]);
        }
    }
    // ---- B fragments: col = w*32 + ct*16 + lr; B[k][col] = Wmat[col][k] ----
    bf16x8 bfr[2][2][2];              // [mat][ct][kb]
    #pragma unroll
    for (int mat = 0; mat < 2; ++mat) {
        const float* __restrict__ Wm = mat ? resW : M;
        #pragma unroll
        for (int ct = 0; ct < 2; ++ct) {
            const float* __restrict__ wrow = &Wm[(w * 32 + ct * 16 + lr) * ID];
            #pragma unroll
            for (int kb = 0; kb < 2; ++kb) {
                const float4 v0 = *(const float4*)&wrow[kb * 32 + lk * 8];
                const float4 v1 = *(const float4*)&wrow[kb * 32 + lk * 8 + 4];
                bfr[mat][ct][kb] = pack8(v0, v1);
            }
        }
    }

    // ---- MFMA: x_t with hi+lo (4 per ct), residual with hi (2 per ct) ----
    f32x4 accx[2], accr[2];
    #pragma unroll
    for (int ct = 0; ct < 2; ++ct) {
        f32x4 a4 = {0.f, 0.f, 0.f, 0.f};
        a4 = __builtin_amdgcn_mfma_f32_16x16x32_bf16(alo[0], bfr[0][ct][0], a4, 0, 0, 0);
        a4 = __builtin_amdgcn_mfma_f32_16x16x32_bf16(alo[1], bfr[0][ct][1], a4, 0, 0, 0);
        a4 = __builtin_amdgcn_mfma_f32_16x16x32_bf16(ahi[0], bfr[0][ct][0], a4, 0, 0, 0);
        a4 = __builtin_amdgcn_mfma_f32_16x16x32_bf16(ahi[1], bfr[0][ct][1], a4, 0, 0, 0);
        accx[ct] = a4;
        f32x4 r4 = {0.f, 0.f, 0.f, 0.f};
        r4 = __builtin_amdgcn_mfma_f32_16x16x32_bf16(ahi[0], bfr[1][ct][0], r4, 0, 0, 0);
        r4 = __builtin_amdgcn_mfma_f32_16x16x32_bf16(ahi[1], bfr[1][ct][1], r4, 0, 0, 0);
        accr[ct] = r4;
    }

    // ---- residual: direct stores (C: col = strip+lr, row = lk*4+q) ----
    #pragma unroll
    for (int ct = 0; ct < 2; ++ct)
        #pragma unroll
        for (int q = 0; q < 4; ++q) {
            const int r = lk * 4 + q;
            const int b = r & 7, sl = r >> 3;
            out[(b * SD + s0 + sl) * OD + w * 32 + ct * 16 + lr] = accr[ct][q];
        }
    // ---- x_t -> LDS for LN ----
    #pragma unroll
    for (int ct = 0; ct < 2; ++ct)
        #pragma unroll
        for (int q = 0; q < 4; ++q)
            Ct[lk * 4 + q][w * 32 + ct * 16 + lr] = accx[ct][q];
    __syncthreads();

    // ---- LN: thread -> (row = t>>4, col-chunk c0 = (t&15)*8) ----
    {
        const int row = t >> 4;
        const int c0  = (t & 15) * 8;
        float sum = 0.f, ssq = 0.f;
        #pragma unroll
        for (int e = 0; e < 8; ++e) {
            const float v = Ct[row][c0 + e];
            sum += v; ssq = fmaf(v, v, ssq);
        }
        #pragma unroll
        for (int m = 1; m < 16; m <<= 1) {
            sum += __shfl_xor(sum, m, 64);
            ssq += __shfl_xor(ssq, m, 64);
        }
        const float mu   = sum * (1.0f / OD);
        const float vr   = ssq * (1.0f / OD) - mu * mu;
        const float rstd = rsqrtf(vr + 1e-5f);

        const float4 g0 = *(const float4*)&gamma[c0];
        const float4 g1 = *(const float4*)&gamma[c0 + 4];
        const float4 b0 = *(const float4*)&beta[c0];
        const float4 b1 = *(const float4*)&beta[c0 + 4];
        const float gv[8] = {g0.x,g0.y,g0.z,g0.w,g1.x,g1.y,g1.z,g1.w};
        const float bv[8] = {b0.x,b0.y,b0.z,b0.w,b1.x,b1.y,b1.z,b1.w};

        union { ushort u[8]; ushortx8 v; } xo;
        #pragma unroll
        for (int e = 0; e < 8; ++e) {
            const float xv = (Ct[row][c0 + e] - mu) * rstd * gv[e] + bv[e];
            xo.u[e] = rne_bf16(xv);
        }
        const int b  = row & 7, sl = row >> 3;
        *(ushortx8*)&xnT[((s0 + sl) * BD + b) * OD + c0] = xo.v;
    }
}

// ---- Kernel B: fused Chebyshev W-gen + MFMA, out += Nk (R14, validated) ----
__global__ __launch_bounds__(512, 6) void nk_kernel(
    const float* __restrict__ P,      // (128,128,6) raw [i][j][g]
    const ushort* __restrict__ xnT,   // [s][b][j] bf16
    float* __restrict__ out)          // (8,1024,128)
{
    const int sc = blockIdx.x;        // s in [sc*SCH, (sc+1)*SCH)
    const int i0 = blockIdx.y * TI;
    const int t  = threadIdx.x;
    const int iw = t >> 7;            // 0..3 local i (W-gen role)
    const int jb = t & 127;
    const int wv = t >> 6;            // 0..7 wave id (MFMA role)
    const int l  = t & 63;

    __shared__ ushort Wl[SS][TI][WPAD];    // 8.7 KB
    __shared__ ushort Xl[SS][BD][WPAD];    // 17.4 KB
    __shared__ float  Cst[SS][BD][TI];     // 1 KB epilogue stage

    float Pv[NBD], kk[NBD], c0[NBD], c1[NBD];
    const int ig = i0 + iw;
    const float s0f = (float)(sc * SCH);
    #pragma unroll
    for (int g = 0; g < NBD; ++g) {
        Pv[g] = P[(ig * OD + jb) * NBD + g];               // L2-hot, once/block
        const float per = (float)(ig * (OD * NBD) + jb * NBD + g + 2); // exact int
        const float rp  = __builtin_amdgcn_rcpf(per);      // revolutions per step
        kk[g] = 2.0f * __builtin_amdgcn_cosf(rp);
        c1[g] = __builtin_amdgcn_cosf(__builtin_amdgcn_fractf(s0f * rp));
        c0[g] = __builtin_amdgcn_cosf(__builtin_amdgcn_fractf((s0f - 1.0f) * rp));
    }

    for (int u = 0; u < SCH / SS; ++u) {
        const int sb = sc * SCH + u * SS;
        {
            const uint4* __restrict__ src = (const uint4*)(xnT + sb * (BD * OD));
            #pragma unroll
            for (int r = 0; r < 2; ++r) {
                const int e  = t + 512 * r;       // uint4 index (1024 total)
                const uint4 v = src[e];
                const int eo = e << 3;            // bf16 elem offset
                const int si = eo >> 10;
                const int b  = (eo >> 7) & 7;
                const int j0 = eo & 127;
                *(uint4*)&Xl[si][b][j0] = v;
            }
        }
        #pragma unroll
        for (int ssi = 0; ssi < SS; ++ssi) {
            float wvv = 0.f;
            #pragma unroll
            for (int g = 0; g < NBD; ++g) wvv = fmaf(Pv[g], c1[g], wvv);
            #pragma unroll
            for (int g = 0; g < NBD; ++g) {
                const float cn = fmaf(kk[g], c1[g], -c0[g]);   // Chebyshev step
                c0[g] = c1[g]; c1[g] = cn;
            }
            Wl[ssi][iw][jb] = rne_bf16(wvv);
        }
        __syncthreads();
        {
            f32x4 acc4 = {0.f, 0.f, 0.f, 0.f};
            #pragma unroll
            for (int m = 0; m < 4; ++m) {
                const bf16x8 a = *(const bf16x8*)&Xl[wv][l & 7][m * 32 + (l >> 4) * 8];
                const bf16x8 b = *(const bf16x8*)&Wl[wv][l & 3][m * 32 + (l >> 4) * 8];
                acc4 = __builtin_amdgcn_mfma_f32_16x16x32_bf16(a, b, acc4, 0, 0, 0);
            }
            const int col  = l & 15;
            const int rowg = l >> 4;
            if (col < TI && rowg < 2) {
                #pragma unroll
                for (int q = 0; q < 4; ++q)
                    Cst[wv][rowg * 4 + q][col] = acc4[q];
            }
        }
        __syncthreads();
        if (t < SS * BD * TI) {
            const int ii  = t & 3;
            const int b   = (t >> 2) & 7;
            const int sl2 = t >> 5;
            out[(b * SD + sb + sl2) * OD + i0 + ii] += Cst[sl2][b][ii];
        }
        __syncthreads();
    }
}

extern "C" void kernel_launch(void* const* d_in, const int* in_sizes, int n_in,
                              void* d_out, int out_size, void* d_ws, size_t ws_size,
                              hipStream_t stream) {
    const float* seq   = (const float*)d_in[0];
    const float* M     = (const float*)d_in[1];
    const float* P     = (const float*)d_in[2];
    const float* resW  = (const float*)d_in[3];
    const float* gamma = (const float*)d_in[4];
    const float* beta  = (const float*)d_in[5];
    float* out = (float*)d_out;

    ushort* xnT = (ushort*)d_ws;                        // 2 MB bf16 [s][b][j]

    ln_mfma<<<dim3(SD / 2), dim3(256), 0, stream>>>(seq, M, resW, gamma, beta,
                                                    xnT, out);
    nk_kernel<<<dim3(SD / SCH, OD / TI), dim3(512), 0, stream>>>(P, xnT, out);
}